// Round 19
// baseline (196.739 us; speedup 1.0000x reference)
//
#include <hip/hip_runtime.h>
#include <hip/hip_bf16.h>
#include <stdint.h>

typedef unsigned short u16;
typedef __attribute__((ext_vector_type(8))) short bf16x8;   // 8 bf16 in 4 VGPRs
typedef __attribute__((ext_vector_type(4))) short bf16x4;   // 4 bf16 in 2 VGPRs
typedef __attribute__((ext_vector_type(4))) float f32x4;

__device__ __forceinline__ u16 f2bf(float f) {
    union { float f; unsigned int i; } c; c.f = f;
    unsigned int x = c.i;
    return (u16)((x + 0x7FFFu + ((x >> 16) & 1u)) >> 16);   // RNE
}
__device__ __forceinline__ u16 f2bf_fast(float f) {         // tie-away, 2 VALU
    union { float f; unsigned int i; } c; c.f = f;
    return (u16)((c.i + 0x8000u) >> 16);
}

// 16x16x16 bf16 MFMA (A/B = 2 VGPRs). Builtin if present, else inline asm.
__device__ __forceinline__ f32x4 mfma16(bf16x4 a, bf16x4 b, f32x4 c) {
#if __has_builtin(__builtin_amdgcn_mfma_f32_16x16x16bf16_1k)
    return __builtin_amdgcn_mfma_f32_16x16x16bf16_1k(a, b, c, 0, 0, 0);
#else
    asm volatile("v_mfma_f32_16x16x16_bf16 %0, %1, %2, %0"
                 : "+v"(c) : "v"(a), "v"(b));
    return c;
#endif
}

// async global->LDS, 16B per lane; LDS dst = uniform base + lane*16
__device__ __forceinline__ void glds16(const u16* g, u16* l) {
    __builtin_amdgcn_global_load_lds(
        (const __attribute__((address_space(1))) void*)g,
        (__attribute__((address_space(3))) void*)l, 16, 0, 0);
}

// manual sync: raw barrier + partial vmcnt waits.
__device__ __forceinline__ void bar() { asm volatile("s_barrier" ::: "memory"); }
template <int N> __device__ __forceinline__ void waitv() {
    if constexpr (N == 0)      asm volatile("s_waitcnt vmcnt(0)" ::: "memory");
    else if constexpr (N == 2) asm volatile("s_waitcnt vmcnt(2)" ::: "memory");
    else if constexpr (N == 3) asm volatile("s_waitcnt vmcnt(3)" ::: "memory");
    else if constexpr (N == 4) asm volatile("s_waitcnt vmcnt(4)" ::: "memory");
    else if constexpr (N == 6) asm volatile("s_waitcnt vmcnt(6)" ::: "memory");
    else if constexpr (N == 8) asm volatile("s_waitcnt vmcnt(8)" ::: "memory");
}

// ---------------------------------------------------------------------------
// fp32 -> bf16 conversion of z, wq, wk, wv, wo (one kernel, 8 elems/thread)
// ---------------------------------------------------------------------------
__global__ __launch_bounds__(256) void convert_all(
    const float* __restrict__ z, const float* __restrict__ wq,
    const float* __restrict__ wk, const float* __restrict__ wv,
    const float* __restrict__ wo,
    u16* __restrict__ zb, u16* __restrict__ wqb, u16* __restrict__ wkb,
    u16* __restrict__ wvb, u16* __restrict__ wob)
{
    int g = blockIdx.x * 256 + threadIdx.x;      // group of 8 elements
    const float* s; u16* d;
    if (g < 786432)       { s = z;  d = zb;  }
    else if (g < 860160)  { s = wq; d = wqb; g -= 786432; }
    else if (g < 933888)  { s = wk; d = wkb; g -= 860160; }
    else if (g < 1007616) { s = wv; d = wvb; g -= 933888; }
    else                  { s = wo; d = wob; g -= 1007616; }
    float4 a = *(const float4*)(s + (size_t)g * 8);
    float4 b = *(const float4*)(s + (size_t)g * 8 + 4);
    u16 t[8] = {f2bf(a.x), f2bf(a.y), f2bf(a.z), f2bf(a.w),
                f2bf(b.x), f2bf(b.y), f2bf(b.z), f2bf(b.w)};
    *(uint4*)(d + (size_t)g * 8) = *(const uint4*)t;
}

// ---------------------------------------------------------------------------
// QKV r17: 256 threads (4 waves 2x2), tile 128x256 (per-wave 64x128:
// 32 MFMA / 12 ds_read_b128 per K-step = 2.67 ratio vs 2.0 before; barriers
// per FLOP halved while KEEPING 4 waves -- the r1/r3 regression came from
// 2-wave blocks). BK 32, same 2-bar glds pipeline. 6 glds/thread/tile,
// steady 12 outstanding, waitv<6> drains oldest tile. LDS 48 KB dbuf.
// Grid 576: n0 = (d/64)*256 (9 panels, 256 | 768), m0 = (d%64)*128.
// ---------------------------------------------------------------------------
__global__ __launch_bounds__(256, 2) void qkv_gemm(
    const u16* __restrict__ zb, const u16* __restrict__ wqb,
    const u16* __restrict__ wkb, const u16* __restrict__ wvb,
    u16* __restrict__ qkb, u16* __restrict__ vt)
{
    __shared__ __align__(16) u16 As[8192], Bs[16384];  // dbuf: A 2x4096, B 2x8192
    const int d = blockIdx.x;
    const int n0 = (d >> 6) * 256, m0 = (d & 63) * 128;
    const u16* Bp;
    if (n0 < 768)       Bp = wqb + (size_t)n0 * 768;
    else if (n0 < 1536) Bp = wkb + (size_t)(n0 - 768) * 768;
    else                Bp = wvb + (size_t)(n0 - 1536) * 768;

    const int t = threadIdx.x;
    const int w = t >> 6, lane = t & 63, quad = lane >> 4, lc = lane & 15;
    const int wm = w >> 1, wn = w & 1;
    const int swz = (lc >> 1) & 3;

    // A staging: 512 cells (128 rows x 4 kq), 2 cells/thread
    const u16* pa[2]; int la[2];
    #pragma unroll
    for (int j = 0; j < 2; j++) {
        const int c = j * 256 + t;
        const int row = c >> 2;
        const int kq = (c & 3) ^ ((row >> 1) & 3);
        pa[j] = &zb[(size_t)(m0 + row) * 768 + kq * 8];
        la[j] = (j * 256 + w * 64) * 8;            // wave-uniform cell base * 8
    }
    // B staging: 1024 cells (256 rows x 4 kq), 4 cells/thread
    const u16* pb[4]; int lb[4];
    #pragma unroll
    for (int j = 0; j < 4; j++) {
        const int c = j * 256 + t;
        const int row = c >> 2;                    // 0..255
        const int kq = (c & 3) ^ ((row >> 1) & 3);
        pb[j] = &Bp[(size_t)row * 768 + kq * 8];
        lb[j] = (j * 256 + w * 64) * 8;
    }

    // prologue: tile0 -> buf0, tile1 -> buf1 (6 glds per thread per tile)
    #pragma unroll
    for (int j = 0; j < 2; j++) glds16(pa[j], As + la[j]);
    #pragma unroll
    for (int j = 0; j < 4; j++) glds16(pb[j], Bs + lb[j]);
    #pragma unroll
    for (int j = 0; j < 2; j++) glds16(pa[j] + 32, As + 4096 + la[j]);
    #pragma unroll
    for (int j = 0; j < 4; j++) glds16(pb[j] + 32, Bs + 8192 + lb[j]);

    f32x4 acc[4][8] = {};
    int buf = 0;
    for (int bk = 0; bk < 24; bk++) {
        if (bk + 1 < 24) waitv<6>(); else waitv<0>();   // tile bk landed
        bar();
        bf16x8 af[4], bfr[8];
        #pragma unroll
        for (int i = 0; i < 4; i++) {
            const int row = 64 * wm + 16 * i + lc;
            af[i] = *(const bf16x8*)&As[buf * 4096 + (row * 4 + (quad ^ swz)) * 8];
        }
        #pragma unroll
        for (int j = 0; j < 8; j++) {
            const int row = 128 * wn + 16 * j + lc;    // 0..255
            bfr[j] = *(const bf16x8*)&Bs[buf * 8192 + (row * 4 + (quad ^ swz)) * 8];
        }
        #pragma unroll
        for (int i = 0; i < 4; i++)
            #pragma unroll
            for (int j = 0; j < 8; j++)
                acc[i][j] = __builtin_amdgcn_mfma_f32_16x16x32_bf16(af[i], bfr[j], acc[i][j], 0, 0, 0);
        bar();                          // all waves' frag reads done
        if (bk + 2 < 24) {              // tile bk+2 -> the buffer just read
            const int k2 = (bk + 2) * 32;
            #pragma unroll
            for (int j = 0; j < 2; j++) glds16(pa[j] + k2, As + buf * 4096 + la[j]);
            #pragma unroll
            for (int j = 0; j < 4; j++) glds16(pb[j] + k2, Bs + buf * 8192 + lb[j]);
        }
        buf ^= 1;
    }

    if (n0 < 1536) {
        #pragma unroll
        for (int i = 0; i < 4; i++)
            #pragma unroll
            for (int j = 0; j < 8; j++) {
                const int col = n0 + 128 * wn + 16 * j + lc;
                #pragma unroll
                for (int r = 0; r < 4; r++) {
                    const int row = m0 + 64 * wm + 16 * i + quad * 4 + r;
                    qkb[(size_t)row * 1536 + col] = f2bf_fast(acc[i][j][r]);
                }
            }
    } else {
        #pragma unroll
        for (int i = 0; i < 4; i++)
            #pragma unroll
            for (int j = 0; j < 8; j++) {
                const int c = (n0 - 1536) + 128 * wn + 16 * j + lc;  // 0..767
                const int h = c >> 6, dd = c & 63;
                const int tok0 = m0 + 64 * wm + 16 * i + quad * 4;
                const int b = tok0 >> 10, n = tok0 & 1023;
                ushort4 pk = { f2bf_fast(acc[i][j][0]), f2bf_fast(acc[i][j][1]),
                               f2bf_fast(acc[i][j][2]), f2bf_fast(acc[i][j][3]) };
                *(ushort4*)&vt[(((size_t)(b * 12 + h)) * 64 + dd) * 1024 + n] = pk;
            }
    }
}

// ---------------------------------------------------------------------------
// oproj r12: out[8192,768](f32) = obuf[8192,768](bf16) x wob[768,768]^T + bo.
// qkv-proven 2-bar manual pipeline; M-tile 64 (MI=2), N-tile 128, BK 32;
// 3 glds/thread/tile; steady 6 outstanding, waitv<3> drains oldest tile.
// XCD-aware 1-D grid (768): n = d/128, m = d%128. LDS 24 KB dbuf.
// ---------------------------------------------------------------------------
__global__ __launch_bounds__(256) void oproj_gemm(
    const u16* __restrict__ ob, const u16* __restrict__ wob,
    const float* __restrict__ bo, float* __restrict__ out)
{
    __shared__ __align__(16) u16 As[4096], Bs[8192];   // dbuf: A 2x2048, B 2x4096
    const int d = blockIdx.x;
    const int n0 = (d >> 7) * 128, m0 = (d & 127) * 64;

    const int t = threadIdx.x;
    const int w = t >> 6, lane = t & 63, quad = lane >> 4, lc = lane & 15;
    const int wm = w >> 1, wn = w & 1;
    const int swz = (lc >> 1) & 3;

    // A staging: 256 cells (64 rows x 4 kq), 1 cell/thread
    const int arow = t >> 2;
    const int akq = (t & 3) ^ ((arow >> 1) & 3);
    const u16* pa = &ob[(size_t)(m0 + arow) * 768 + akq * 8];
    const int la = (w * 64) * 8;                   // wave-uniform cell base * 8
    // B staging: 512 cells, 2 cells/thread
    const u16* pb[2]; int lb[2];
    #pragma unroll
    for (int j = 0; j < 2; j++) {
        const int c = j * 256 + t;
        const int row = c >> 2;
        const int kq = (c & 3) ^ ((row >> 1) & 3);
        pb[j] = &wob[(size_t)(n0 + row) * 768 + kq * 8];
        lb[j] = (j * 256 + w * 64) * 8;
    }

    // prologue: tile0 -> buf0, tile1 -> buf1 (3 glds per thread per tile)
    glds16(pa, As + la);
    glds16(pb[0], Bs + lb[0]);  glds16(pb[1], Bs + lb[1]);
    glds16(pa + 32, As + 2048 + la);
    glds16(pb[0] + 32, Bs + 4096 + lb[0]);  glds16(pb[1] + 32, Bs + 4096 + lb[1]);

    f32x4 acc[2][4] = {};
    int buf = 0;
    for (int bk = 0; bk < 24; bk++) {
        if (bk + 1 < 24) waitv<3>(); else waitv<0>();   // tile bk landed
        bar();
        bf16x8 af[2], bfr[4];
        #pragma unroll
        for (int i = 0; i < 2; i++) {
            const int row = 32 * wm + 16 * i + lc;
            af[i] = *(const bf16x8*)&As[buf * 2048 + (row * 4 + (quad ^ swz)) * 8];
        }
        #pragma unroll
        for (int j = 0; j < 4; j++) {
            const int row = 64 * wn + 16 * j + lc;
            bfr[j] = *(const bf16x8*)&Bs[buf * 4096 + (row * 4 + (quad ^ swz)) * 8];
        }
        #pragma unroll
        for (int i = 0; i < 2; i++)
            #pragma unroll
            for (int j = 0; j < 4; j++)
                acc[i][j] = __builtin_amdgcn_mfma_f32_16x16x32_bf16(af[i], bfr[j], acc[i][j], 0, 0, 0);
        bar();                          // all waves' frag reads done
        if (bk + 2 < 24) {              // tile bk+2 -> the buffer just read
            const int k2 = (bk + 2) * 32;
            glds16(pa + k2, As + buf * 2048 + la);
            glds16(pb[0] + k2, Bs + buf * 4096 + lb[0]);
            glds16(pb[1] + k2, Bs + buf * 4096 + lb[1]);
        }
        buf ^= 1;
    }

    #pragma unroll
    for (int i = 0; i < 2; i++)
        #pragma unroll
        for (int j = 0; j < 4; j++) {
            const int col = n0 + 64 * wn + 16 * j + lc;
            const float bv = bo[col];
            #pragma unroll
            for (int r = 0; r < 4; r++) {
                const int row = m0 + 32 * wm + 16 * i + quad * 4 + r;
                out[(size_t)row * 768 + col] = acc[i][j][r] + bv;
            }
        }
}

// ---------------------------------------------------------------------------
// Flash attention r16-hybrid (r17-measured best): r12 LDS staging/pipeline
// (K dbuf + one-iter prefetch, V glds, same swizzles) + swapped QK^T
// (S^T = mfma(A=K_lds, B=Q_regs)) so P stays in registers and feeds PV
// directly as x16 A-frags. LDS 24 KB.
// ---------------------------------------------------------------------------
__global__ __launch_bounds__(256, 4) void attn_kernel(
    const u16* __restrict__ qkb, const u16* __restrict__ vt,
    u16* __restrict__ obuf)
{
    const int b = blockIdx.x / 12, h = blockIdx.x % 12;
    const int q0 = blockIdx.y * 128;
    const int t = threadIdx.x;
    const int w = t >> 6, lane = t & 63, quad = lane >> 4, lc = lane & 15;

    const u16* Qp  = qkb + (size_t)b * 1024 * 1536 + h * 64;
    const u16* Kp  = Qp + 768;
    const u16* Vtp = vt + ((size_t)(b * 12 + h)) * 64 * 1024;

    __shared__ __align__(16) u16 Ks[2][4096];   // K dbuf: 64 rows x 8 slots x 8 u16
    __shared__ __align__(16) u16 Vts[4096];     // V^T: 64 d x 8 slots x 8 u16, XOR swz

    // K staging: 512 cells, c = j*256 + t (2 cells/thread)  [r12 verbatim]
    const u16* kp[2]; int kl[2];
    #pragma unroll
    for (int j = 0; j < 2; j++) {
        const int c = j * 256 + t;
        const int row = c >> 3;                    // 0..63
        const int kq = (c & 7) ^ ((row >> 1) & 7);
        kp[j] = Kp + (size_t)row * 1536 + kq * 8;
        kl[j] = (j * 256 + w * 64) * 8;            // wave-uniform cell base * 8
    }
    // V staging: 512 cells, c = s*64 + lane, s = 2w+s2 (2 cells/thread) [r12]
    const u16* vp[2]; u16* vl[2];
    #pragma unroll
    for (int s2 = 0; s2 < 2; s2++) {
        const int s = 2 * w + s2;
        const int c = s * 64 + lane;
        const int dd = c >> 3, kq = (c & 7) ^ (dd & 7);
        vp[s2] = Vtp + (size_t)dd * 1024 + kq * 8;
        vl[s2] = &Vts[s * 512];
    }

    // Q as B-frags: n = q row = q0+32w+16rg+lc, k = d = kk*32+quad*8+e
    bf16x8 qf[2][2];
    #pragma unroll
    for (int rg = 0; rg < 2; rg++)
        #pragma unroll
        for (int kk = 0; kk < 2; kk++)
            qf[rg][kk] = *(const bf16x8*)&Qp[(size_t)(q0 + 32 * w + 16 * rg + lc) * 1536
                                             + kk * 32 + quad * 8];

    f32x4 oaccT[2][4] = {};                 // O[q=32w+16rg+4quad+r][d=16jd+lc]
    float lsum[2] = {0.0f, 0.0f};           // partial row sum for q = lc (per rg)
    const float cs = 0.18033688011112042f;  // log2(e) / sqrt(64)
    const int swk = (lc >> 1) & 7;

    waitv<0>();                             // qf drained; clean vmcnt at loop entry
    // prologue: K(0) -> Ks[0]
    glds16(kp[0], &Ks[0][0] + kl[0]);
    glds16(kp[1], &Ks[0][0] + kl[1]);

    for (int kt = 0; kt < 16; kt++) {
        const int kb = kt * 64;
        bar();                              // prior iter's LDS reads done
        glds16(vp[0] + kb, vl[0]);          // V(kt) (2 glds)
        glds16(vp[1] + kb, vl[1]);
        if (kt + 1 < 16) {                  // prefetch K(kt+1) -> other buffer
            const size_t kb1 = (size_t)(kt + 1) * 64 * 1536;
            u16* kd = &Ks[(kt + 1) & 1][0];
            glds16(kp[0] + kb1, kd + kl[0]);
            glds16(kp[1] + kb1, kd + kl[1]);
            waitv<4>();                     // K(kt) landed (V + K(kt+1) in flight)
        } else {
            waitv<2>();                     // K(15) landed (V in flight)
        }
        bar();                              // K visible to all waves

        // S^T = K Q^T : A = K from LDS (reads identical to r12), B = qf.
        // Thread gets S[kv=kb+16jk+4quad+r][q=q0+32w+16rg+lc].
        const u16* Kc = &Ks[kt & 1][0];
        f32x4 st[2][4] = {};
        #pragma unroll
        for (int jk = 0; jk < 4; jk++) {
            const int row = 16 * jk + lc;
            bf16x8 kf0 = *(const bf16x8*)&Kc[(row * 8 + (quad ^ swk)) * 8];
            bf16x8 kf1 = *(const bf16x8*)&Kc[(row * 8 + ((4 + quad) ^ swk)) * 8];
            #pragma unroll
            for (int rg = 0; rg < 2; rg++) {
                st[rg][jk] = __builtin_amdgcn_mfma_f32_16x16x32_bf16(kf0, qf[rg][0], st[rg][jk], 0, 0, 0);
                st[rg][jk] = __builtin_amdgcn_mfma_f32_16x16x32_bf16(kf1, qf[rg][1], st[rg][jk], 0, 0, 0);
            }
        }
        if (kt + 1 < 16) waitv<2>();        // V(kt) landed (K(kt+1) stays in flight)
        else             waitv<0>();
        bar();                              // V visible

        // P = exp2(S*cs) in REGISTERS; pack own 4 values as x16 A-frag
        bf16x4 pf[2][4];
        #pragma unroll
        for (int rg = 0; rg < 2; rg++)
            #pragma unroll
            for (int jk = 0; jk < 4; jk++) {
                float p0 = __builtin_amdgcn_exp2f(st[rg][jk][0] * cs);
                float p1 = __builtin_amdgcn_exp2f(st[rg][jk][1] * cs);
                float p2 = __builtin_amdgcn_exp2f(st[rg][jk][2] * cs);
                float p3 = __builtin_amdgcn_exp2f(st[rg][jk][3] * cs);
                lsum[rg] += (p0 + p1) + (p2 + p3);
                bf16x4 pk;
                pk[0] = (short)f2bf_fast(p0);
                pk[1] = (short)f2bf_fast(p1);
                pk[2] = (short)f2bf_fast(p2);
                pk[3] = (short)f2bf_fast(p3);
                pf[rg][jk] = pk;
            }

        // O^T += P V : B = V from LDS (n = d = 16jd+lc, k = kv = 16jk+4quad+e)
        #pragma unroll
        for (int jk = 0; jk < 4; jk++) {
            bf16x4 vf[4];
            #pragma unroll
            for (int jd = 0; jd < 4; jd++) {
                const int dd = 16 * jd + lc;
                const int g = 2 * jk + (quad >> 1);
                vf[jd] = *(const bf16x4*)&Vts[(dd * 8 + (g ^ (dd & 7))) * 8 + 4 * (quad & 1)];
            }
            #pragma unroll
            for (int rg = 0; rg < 2; rg++)
                #pragma unroll
                for (int jd = 0; jd < 4; jd++)
                    oaccT[rg][jd] = mfma16(pf[rg][jk], vf[jd], oaccT[rg][jd]);
        }
    }

    // reduce lsum across the 4 quads holding each q (lanes lc, lc+16, +32, +48)
    float invl[2];
    #pragma unroll
    for (int rg = 0; rg < 2; rg++) {
        lsum[rg] += __shfl_xor(lsum[rg], 16, 64);
        lsum[rg] += __shfl_xor(lsum[rg], 32, 64);
        invl[rg] = __builtin_amdgcn_rcpf(lsum[rg]);
    }

    // epilogue: thread stores O[q=q0+32w+16rg+4quad+r][d=16jd+lc]; fetch the
    // inverse sum for row 4quad+r from the lane with lc = 4quad+r (own quad).
    #pragma unroll
    for (int rg = 0; rg < 2; rg++) {
        float invq[4];
        #pragma unroll
        for (int r = 0; r < 4; r++)
            invq[r] = __shfl(invl[rg], (lane & 48) + 4 * quad + r, 64);
        #pragma unroll
        for (int jd = 0; jd < 4; jd++)
            #pragma unroll
            for (int r = 0; r < 4; r++) {
                const int row = q0 + 32 * w + 16 * rg + 4 * quad + r;
                const int col = h * 64 + 16 * jd + lc;
                obuf[((size_t)b * 1024 + row) * 768 + col] = f2bf_fast(oaccT[rg][jd][r] * invq[r]);
            }
    }
}

extern "C" void kernel_launch(void* const* d_in, const int* in_sizes, int n_in,
                              void* d_out, int out_size, void* d_ws, size_t ws_size,
                              hipStream_t stream) {
    const float* z  = (const float*)d_in[0];
    const float* wq = (const float*)d_in[1];
    const float* wk = (const float*)d_in[2];
    const float* wv = (const float*)d_in[3];
    const float* wo = (const float*)d_in[4];
    const float* bo = (const float*)d_in[5];

    u16* ws16 = (u16*)d_ws;
    u16* zb   = ws16;                 // 6,291,456 u16 (reused as obuf)
    u16* wqb  = zb  + 6291456;        //   589,824 each
    u16* wkb  = wqb + 589824;
    u16* wvb  = wkb + 589824;
    u16* wob  = wvb + 589824;
    u16* vt   = wob + 589824;         // 6,291,456   (total 29.9 MB)
    u16* qkb  = (u16*)d_out;          // 12,582,912 u16 == d_out bytes; dead before oproj
    u16* obuf = zb;                   // zb dead after qkv_gemm
    float* out = (float*)d_out;

    convert_all<<<4224, 256, 0, stream>>>(z, wq, wk, wv, wo, zb, wqb, wkb, wvb, wob);
    qkv_gemm<<<576, 256, 0, stream>>>(zb, wqb, wkb, wvb, qkb, vt);
    attn_kernel<<<dim3(96, 8), 256, 0, stream>>>(qkb, vt, obuf);
    oproj_gemm<<<768, 256, 0, stream>>>(obuf, wob, bo, out);
}

// Round 22
// 190.579 us; speedup vs baseline: 1.0323x; 1.0323x over previous
//
#include <hip/hip_runtime.h>
#include <hip/hip_bf16.h>
#include <stdint.h>

typedef unsigned short u16;
typedef __attribute__((ext_vector_type(8))) short bf16x8;   // 8 bf16 in 4 VGPRs
typedef __attribute__((ext_vector_type(4))) short bf16x4;   // 4 bf16 in 2 VGPRs
typedef __attribute__((ext_vector_type(4))) float f32x4;

__device__ __forceinline__ u16 f2bf(float f) {
    union { float f; unsigned int i; } c; c.f = f;
    unsigned int x = c.i;
    return (u16)((x + 0x7FFFu + ((x >> 16) & 1u)) >> 16);   // RNE
}
__device__ __forceinline__ u16 f2bf_fast(float f) {         // tie-away, 2 VALU
    union { float f; unsigned int i; } c; c.f = f;
    return (u16)((c.i + 0x8000u) >> 16);
}

// 16x16x16 bf16 MFMA (A/B = 2 VGPRs). Builtin if present, else inline asm.
__device__ __forceinline__ f32x4 mfma16(bf16x4 a, bf16x4 b, f32x4 c) {
#if __has_builtin(__builtin_amdgcn_mfma_f32_16x16x16bf16_1k)
    return __builtin_amdgcn_mfma_f32_16x16x16bf16_1k(a, b, c, 0, 0, 0);
#else
    asm volatile("v_mfma_f32_16x16x16_bf16 %0, %1, %2, %0"
                 : "+v"(c) : "v"(a), "v"(b));
    return c;
#endif
}

// async global->LDS, 16B per lane; LDS dst = uniform base + lane*16
__device__ __forceinline__ void glds16(const u16* g, u16* l) {
    __builtin_amdgcn_global_load_lds(
        (const __attribute__((address_space(1))) void*)g,
        (__attribute__((address_space(3))) void*)l, 16, 0, 0);
}

// manual sync: raw barrier + partial vmcnt waits.
__device__ __forceinline__ void bar() { asm volatile("s_barrier" ::: "memory"); }
template <int N> __device__ __forceinline__ void waitv() {
    if constexpr (N == 0)      asm volatile("s_waitcnt vmcnt(0)" ::: "memory");
    else if constexpr (N == 2) asm volatile("s_waitcnt vmcnt(2)" ::: "memory");
    else if constexpr (N == 3) asm volatile("s_waitcnt vmcnt(3)" ::: "memory");
    else if constexpr (N == 4) asm volatile("s_waitcnt vmcnt(4)" ::: "memory");
    else if constexpr (N == 8) asm volatile("s_waitcnt vmcnt(8)" ::: "memory");
}

// ---------------------------------------------------------------------------
// fp32 -> bf16 conversion of z, wq, wk, wv, wo (one kernel, 8 elems/thread)
// ---------------------------------------------------------------------------
__global__ __launch_bounds__(256) void convert_all(
    const float* __restrict__ z, const float* __restrict__ wq,
    const float* __restrict__ wk, const float* __restrict__ wv,
    const float* __restrict__ wo,
    u16* __restrict__ zb, u16* __restrict__ wqb, u16* __restrict__ wkb,
    u16* __restrict__ wvb, u16* __restrict__ wob)
{
    int g = blockIdx.x * 256 + threadIdx.x;      // group of 8 elements
    const float* s; u16* d;
    if (g < 786432)       { s = z;  d = zb;  }
    else if (g < 860160)  { s = wq; d = wqb; g -= 786432; }
    else if (g < 933888)  { s = wk; d = wkb; g -= 860160; }
    else if (g < 1007616) { s = wv; d = wvb; g -= 933888; }
    else                  { s = wo; d = wob; g -= 1007616; }
    float4 a = *(const float4*)(s + (size_t)g * 8);
    float4 b = *(const float4*)(s + (size_t)g * 8 + 4);
    u16 t[8] = {f2bf(a.x), f2bf(a.y), f2bf(a.z), f2bf(a.w),
                f2bf(b.x), f2bf(b.y), f2bf(b.z), f2bf(b.w)};
    *(uint4*)(d + (size_t)g * 8) = *(const uint4*)t;
}

// ---------------------------------------------------------------------------
// QKV (measured plateau, ~50us): 256 threads (4 waves 2x2), tile 128x128,
// BK 32, manual 2-bar glds pipeline, XCD-aware 1-D grid (1152). LDS 32 KB.
// Structural record: 2-wave wide (r3: 63us), 3-buf deep (r4: 52us),
// 4-wave 128x256 (r19: 54us, occupancy halved) all lose -- occupancy is
// the binding constraint at this 24-K-step shape.
// ---------------------------------------------------------------------------
__global__ __launch_bounds__(256) void qkv_gemm(
    const u16* __restrict__ zb, const u16* __restrict__ wqb,
    const u16* __restrict__ wkb, const u16* __restrict__ wvb,
    u16* __restrict__ qkb, u16* __restrict__ vt)
{
    __shared__ __align__(16) u16 As[8192], Bs[8192];   // dbuf: 4096 u16 per buffer
    const int d = blockIdx.x;
    const int n0 = (d >> 6) * 128, m0 = (d & 63) * 128;
    const u16* Bp;
    if (n0 < 768)       Bp = wqb + (size_t)n0 * 768;
    else if (n0 < 1536) Bp = wkb + (size_t)(n0 - 768) * 768;
    else                Bp = wvb + (size_t)(n0 - 1536) * 768;

    const int t = threadIdx.x;
    const int w = t >> 6, lane = t & 63, quad = lane >> 4, lc = lane & 15;
    const int wm = w >> 1, wn = w & 1;
    const int swz = (lc >> 1) & 3;

    const u16* pa[2]; const u16* pb[2]; int la[2], lb[2];
    #pragma unroll
    for (int j = 0; j < 2; j++) {
        const int c = j * 256 + t;
        const int row = c >> 2;
        const int kq = (c & 3) ^ ((row >> 1) & 3);
        pa[j] = &zb[(size_t)(m0 + row) * 768 + kq * 8];
        pb[j] = &Bp[(size_t)row * 768 + kq * 8];
        la[j] = lb[j] = (j * 256 + w * 64) * 8;    // wave-uniform cell base * 8
    }

    // prologue: tile0 -> buf0, tile1 -> buf1 (4 glds per thread per tile)
    glds16(pa[0], As + la[0]);  glds16(pa[1], As + la[1]);
    glds16(pb[0], Bs + lb[0]);  glds16(pb[1], Bs + lb[1]);
    glds16(pa[0] + 32, As + 4096 + la[0]);  glds16(pa[1] + 32, As + 4096 + la[1]);
    glds16(pb[0] + 32, Bs + 4096 + lb[0]);  glds16(pb[1] + 32, Bs + 4096 + lb[1]);

    f32x4 acc[4][4] = {};
    int buf = 0;
    for (int bk = 0; bk < 24; bk++) {
        if (bk + 1 < 24) waitv<4>(); else waitv<0>();   // tile bk landed
        bar();
        bf16x8 af[4], bfr[4];
        #pragma unroll
        for (int i = 0; i < 4; i++) {
            const int row = 64 * wm + 16 * i + lc;
            af[i] = *(const bf16x8*)&As[buf * 4096 + (row * 4 + (quad ^ swz)) * 8];
        }
        #pragma unroll
        for (int j = 0; j < 4; j++) {
            const int row = 64 * wn + 16 * j + lc;
            bfr[j] = *(const bf16x8*)&Bs[buf * 4096 + (row * 4 + (quad ^ swz)) * 8];
        }
        #pragma unroll
        for (int i = 0; i < 4; i++)
            #pragma unroll
            for (int j = 0; j < 4; j++)
                acc[i][j] = __builtin_amdgcn_mfma_f32_16x16x32_bf16(af[i], bfr[j], acc[i][j], 0, 0, 0);
        bar();                          // all waves' frag reads done
        if (bk + 2 < 24) {              // tile bk+2 -> the buffer just read
            const int k2 = (bk + 2) * 32;
            glds16(pa[0] + k2, As + buf * 4096 + la[0]);
            glds16(pa[1] + k2, As + buf * 4096 + la[1]);
            glds16(pb[0] + k2, Bs + buf * 4096 + lb[0]);
            glds16(pb[1] + k2, Bs + buf * 4096 + lb[1]);
        }
        buf ^= 1;
    }

    if (n0 < 1536) {
        #pragma unroll
        for (int i = 0; i < 4; i++)
            #pragma unroll
            for (int j = 0; j < 4; j++) {
                const int col = n0 + 64 * wn + 16 * j + lc;
                #pragma unroll
                for (int r = 0; r < 4; r++) {
                    const int row = m0 + 64 * wm + 16 * i + quad * 4 + r;
                    qkb[(size_t)row * 1536 + col] = f2bf_fast(acc[i][j][r]);
                }
            }
    } else {
        #pragma unroll
        for (int i = 0; i < 4; i++)
            #pragma unroll
            for (int j = 0; j < 4; j++) {
                const int c = (n0 - 1536) + 64 * wn + 16 * j + lc;   // 0..767
                const int h = c >> 6, dd = c & 63;
                const int tok0 = m0 + 64 * wm + 16 * i + quad * 4;
                const int b = tok0 >> 10, n = tok0 & 1023;
                ushort4 pk = { f2bf_fast(acc[i][j][0]), f2bf_fast(acc[i][j][1]),
                               f2bf_fast(acc[i][j][2]), f2bf_fast(acc[i][j][3]) };
                *(ushort4*)&vt[(((size_t)(b * 12 + h)) * 64 + dd) * 1024 + n] = pk;
            }
    }
}

// ---------------------------------------------------------------------------
// oproj r12: out[8192,768](f32) = obuf[8192,768](bf16) x wob[768,768]^T + bo.
// qkv-proven 2-bar manual pipeline; M-tile 64 (MI=2), N-tile 128, BK 32;
// 3 glds/thread/tile; steady 6 outstanding, waitv<3> drains oldest tile.
// XCD-aware 1-D grid (768): n = d/128, m = d%128. LDS 24 KB dbuf.
// ---------------------------------------------------------------------------
__global__ __launch_bounds__(256) void oproj_gemm(
    const u16* __restrict__ ob, const u16* __restrict__ wob,
    const float* __restrict__ bo, float* __restrict__ out)
{
    __shared__ __align__(16) u16 As[4096], Bs[8192];   // dbuf: A 2x2048, B 2x4096
    const int d = blockIdx.x;
    const int n0 = (d >> 7) * 128, m0 = (d & 127) * 64;

    const int t = threadIdx.x;
    const int w = t >> 6, lane = t & 63, quad = lane >> 4, lc = lane & 15;
    const int wm = w >> 1, wn = w & 1;
    const int swz = (lc >> 1) & 3;

    // A staging: 256 cells (64 rows x 4 kq), 1 cell/thread
    const int arow = t >> 2;
    const int akq = (t & 3) ^ ((arow >> 1) & 3);
    const u16* pa = &ob[(size_t)(m0 + arow) * 768 + akq * 8];
    const int la = (w * 64) * 8;                   // wave-uniform cell base * 8
    // B staging: 512 cells, 2 cells/thread
    const u16* pb[2]; int lb[2];
    #pragma unroll
    for (int j = 0; j < 2; j++) {
        const int c = j * 256 + t;
        const int row = c >> 2;
        const int kq = (c & 3) ^ ((row >> 1) & 3);
        pb[j] = &wob[(size_t)(n0 + row) * 768 + kq * 8];
        lb[j] = (j * 256 + w * 64) * 8;
    }

    // prologue: tile0 -> buf0, tile1 -> buf1 (3 glds per thread per tile)
    glds16(pa, As + la);
    glds16(pb[0], Bs + lb[0]);  glds16(pb[1], Bs + lb[1]);
    glds16(pa + 32, As + 2048 + la);
    glds16(pb[0] + 32, Bs + 4096 + lb[0]);  glds16(pb[1] + 32, Bs + 4096 + lb[1]);

    f32x4 acc[2][4] = {};
    int buf = 0;
    for (int bk = 0; bk < 24; bk++) {
        if (bk + 1 < 24) waitv<3>(); else waitv<0>();   // tile bk landed
        bar();
        bf16x8 af[2], bfr[4];
        #pragma unroll
        for (int i = 0; i < 2; i++) {
            const int row = 32 * wm + 16 * i + lc;
            af[i] = *(const bf16x8*)&As[buf * 2048 + (row * 4 + (quad ^ swz)) * 8];
        }
        #pragma unroll
        for (int j = 0; j < 4; j++) {
            const int row = 64 * wn + 16 * j + lc;
            bfr[j] = *(const bf16x8*)&Bs[buf * 4096 + (row * 4 + (quad ^ swz)) * 8];
        }
        #pragma unroll
        for (int i = 0; i < 2; i++)
            #pragma unroll
            for (int j = 0; j < 4; j++)
                acc[i][j] = __builtin_amdgcn_mfma_f32_16x16x32_bf16(af[i], bfr[j], acc[i][j], 0, 0, 0);
        bar();                          // all waves' frag reads done
        if (bk + 2 < 24) {              // tile bk+2 -> the buffer just read
            const int k2 = (bk + 2) * 32;
            glds16(pa + k2, As + buf * 2048 + la);
            glds16(pb[0] + k2, Bs + buf * 4096 + lb[0]);
            glds16(pb[1] + k2, Bs + buf * 4096 + lb[1]);
        }
        buf ^= 1;
    }

    #pragma unroll
    for (int i = 0; i < 2; i++)
        #pragma unroll
        for (int j = 0; j < 4; j++) {
            const int col = n0 + 64 * wn + 16 * j + lc;
            const float bv = bo[col];
            #pragma unroll
            for (int r = 0; r < 4; r++) {
                const int row = m0 + 32 * wm + 16 * i + quad * 4 + r;
                out[(size_t)row * 768 + col] = acc[i][j][r] + bv;
            }
        }
}

// ---------------------------------------------------------------------------
// Flash attention r16-hybrid (r17-measured best): r12 LDS staging/pipeline
// (K dbuf + one-iter prefetch, V glds, same swizzles) + swapped QK^T
// (S^T = mfma(A=K_lds, B=Q_regs)) so P stays in registers and feeds PV
// directly as x16 A-frags. LDS 24 KB.
// ---------------------------------------------------------------------------
__global__ __launch_bounds__(256, 4) void attn_kernel(
    const u16* __restrict__ qkb, const u16* __restrict__ vt,
    u16* __restrict__ obuf)
{
    const int b = blockIdx.x / 12, h = blockIdx.x % 12;
    const int q0 = blockIdx.y * 128;
    const int t = threadIdx.x;
    const int w = t >> 6, lane = t & 63, quad = lane >> 4, lc = lane & 15;

    const u16* Qp  = qkb + (size_t)b * 1024 * 1536 + h * 64;
    const u16* Kp  = Qp + 768;
    const u16* Vtp = vt + ((size_t)(b * 12 + h)) * 64 * 1024;

    __shared__ __align__(16) u16 Ks[2][4096];   // K dbuf: 64 rows x 8 slots x 8 u16
    __shared__ __align__(16) u16 Vts[4096];     // V^T: 64 d x 8 slots x 8 u16, XOR swz

    // K staging: 512 cells, c = j*256 + t (2 cells/thread)  [r12 verbatim]
    const u16* kp[2]; int kl[2];
    #pragma unroll
    for (int j = 0; j < 2; j++) {
        const int c = j * 256 + t;
        const int row = c >> 3;                    // 0..63
        const int kq = (c & 7) ^ ((row >> 1) & 7);
        kp[j] = Kp + (size_t)row * 1536 + kq * 8;
        kl[j] = (j * 256 + w * 64) * 8;            // wave-uniform cell base * 8
    }
    // V staging: 512 cells, c = s*64 + lane, s = 2w+s2 (2 cells/thread) [r12]
    const u16* vp[2]; u16* vl[2];
    #pragma unroll
    for (int s2 = 0; s2 < 2; s2++) {
        const int s = 2 * w + s2;
        const int c = s * 64 + lane;
        const int dd = c >> 3, kq = (c & 7) ^ (dd & 7);
        vp[s2] = Vtp + (size_t)dd * 1024 + kq * 8;
        vl[s2] = &Vts[s * 512];
    }

    // Q as B-frags: n = q row = q0+32w+16rg+lc, k = d = kk*32+quad*8+e
    bf16x8 qf[2][2];
    #pragma unroll
    for (int rg = 0; rg < 2; rg++)
        #pragma unroll
        for (int kk = 0; kk < 2; kk++)
            qf[rg][kk] = *(const bf16x8*)&Qp[(size_t)(q0 + 32 * w + 16 * rg + lc) * 1536
                                             + kk * 32 + quad * 8];

    f32x4 oaccT[2][4] = {};                 // O[q=32w+16rg+4quad+r][d=16jd+lc]
    float lsum[2] = {0.0f, 0.0f};           // partial row sum for q = lc (per rg)
    const float cs = 0.18033688011112042f;  // log2(e) / sqrt(64)
    const int swk = (lc >> 1) & 7;

    waitv<0>();                             // qf drained; clean vmcnt at loop entry
    // prologue: K(0) -> Ks[0]
    glds16(kp[0], &Ks[0][0] + kl[0]);
    glds16(kp[1], &Ks[0][0] + kl[1]);

    for (int kt = 0; kt < 16; kt++) {
        const int kb = kt * 64;
        bar();                              // prior iter's LDS reads done
        glds16(vp[0] + kb, vl[0]);          // V(kt) (2 glds)
        glds16(vp[1] + kb, vl[1]);
        if (kt + 1 < 16) {                  // prefetch K(kt+1) -> other buffer
            const size_t kb1 = (size_t)(kt + 1) * 64 * 1536;
            u16* kd = &Ks[(kt + 1) & 1][0];
            glds16(kp[0] + kb1, kd + kl[0]);
            glds16(kp[1] + kb1, kd + kl[1]);
            waitv<4>();                     // K(kt) landed (V + K(kt+1) in flight)
        } else {
            waitv<2>();                     // K(15) landed (V in flight)
        }
        bar();                              // K visible to all waves

        // S^T = K Q^T : A = K from LDS (reads identical to r12), B = qf.
        // Thread gets S[kv=kb+16jk+4quad+r][q=q0+32w+16rg+lc].
        const u16* Kc = &Ks[kt & 1][0];
        f32x4 st[2][4] = {};
        #pragma unroll
        for (int jk = 0; jk < 4; jk++) {
            const int row = 16 * jk + lc;
            bf16x8 kf0 = *(const bf16x8*)&Kc[(row * 8 + (quad ^ swk)) * 8];
            bf16x8 kf1 = *(const bf16x8*)&Kc[(row * 8 + ((4 + quad) ^ swk)) * 8];
            #pragma unroll
            for (int rg = 0; rg < 2; rg++) {
                st[rg][jk] = __builtin_amdgcn_mfma_f32_16x16x32_bf16(kf0, qf[rg][0], st[rg][jk], 0, 0, 0);
                st[rg][jk] = __builtin_amdgcn_mfma_f32_16x16x32_bf16(kf1, qf[rg][1], st[rg][jk], 0, 0, 0);
            }
        }
        if (kt + 1 < 16) waitv<2>();        // V(kt) landed (K(kt+1) stays in flight)
        else             waitv<0>();
        bar();                              // V visible

        // P = exp2(S*cs) in REGISTERS; pack own 4 values as x16 A-frag
        bf16x4 pf[2][4];
        #pragma unroll
        for (int rg = 0; rg < 2; rg++)
            #pragma unroll
            for (int jk = 0; jk < 4; jk++) {
                float p0 = __builtin_amdgcn_exp2f(st[rg][jk][0] * cs);
                float p1 = __builtin_amdgcn_exp2f(st[rg][jk][1] * cs);
                float p2 = __builtin_amdgcn_exp2f(st[rg][jk][2] * cs);
                float p3 = __builtin_amdgcn_exp2f(st[rg][jk][3] * cs);
                lsum[rg] += (p0 + p1) + (p2 + p3);
                bf16x4 pk;
                pk[0] = (short)f2bf_fast(p0);
                pk[1] = (short)f2bf_fast(p1);
                pk[2] = (short)f2bf_fast(p2);
                pk[3] = (short)f2bf_fast(p3);
                pf[rg][jk] = pk;
            }

        // O^T += P V : B = V from LDS (n = d = 16jd+lc, k = kv = 16jk+4quad+e)
        #pragma unroll
        for (int jk = 0; jk < 4; jk++) {
            bf16x4 vf[4];
            #pragma unroll
            for (int jd = 0; jd < 4; jd++) {
                const int dd = 16 * jd + lc;
                const int g = 2 * jk + (quad >> 1);
                vf[jd] = *(const bf16x4*)&Vts[(dd * 8 + (g ^ (dd & 7))) * 8 + 4 * (quad & 1)];
            }
            #pragma unroll
            for (int rg = 0; rg < 2; rg++)
                #pragma unroll
                for (int jd = 0; jd < 4; jd++)
                    oaccT[rg][jd] = mfma16(pf[rg][jk], vf[jd], oaccT[rg][jd]);
        }
    }

    // reduce lsum across the 4 quads holding each q (lanes lc, lc+16, +32, +48)
    float invl[2];
    #pragma unroll
    for (int rg = 0; rg < 2; rg++) {
        lsum[rg] += __shfl_xor(lsum[rg], 16, 64);
        lsum[rg] += __shfl_xor(lsum[rg], 32, 64);
        invl[rg] = __builtin_amdgcn_rcpf(lsum[rg]);
    }

    // epilogue: thread stores O[q=q0+32w+16rg+4quad+r][d=16jd+lc]; fetch the
    // inverse sum for row 4quad+r from the lane with lc = 4quad+r (own quad).
    #pragma unroll
    for (int rg = 0; rg < 2; rg++) {
        float invq[4];
        #pragma unroll
        for (int r = 0; r < 4; r++)
            invq[r] = __shfl(invl[rg], (lane & 48) + 4 * quad + r, 64);
        #pragma unroll
        for (int jd = 0; jd < 4; jd++)
            #pragma unroll
            for (int r = 0; r < 4; r++) {
                const int row = q0 + 32 * w + 16 * rg + 4 * quad + r;
                const int col = h * 64 + 16 * jd + lc;
                obuf[((size_t)b * 1024 + row) * 768 + col] = f2bf_fast(oaccT[rg][jd][r] * invq[r]);
            }
    }
}

extern "C" void kernel_launch(void* const* d_in, const int* in_sizes, int n_in,
                              void* d_out, int out_size, void* d_ws, size_t ws_size,
                              hipStream_t stream) {
    const float* z  = (const float*)d_in[0];
    const float* wq = (const float*)d_in[1];
    const float* wk = (const float*)d_in[2];
    const float* wv = (const float*)d_in[3];
    const float* wo = (const float*)d_in[4];
    const float* bo = (const float*)d_in[5];

    u16* ws16 = (u16*)d_ws;
    u16* zb   = ws16;                 // 6,291,456 u16 (reused as obuf)
    u16* wqb  = zb  + 6291456;        //   589,824 each
    u16* wkb  = wqb + 589824;
    u16* wvb  = wkb + 589824;
    u16* wob  = wvb + 589824;
    u16* vt   = wob + 589824;         // 6,291,456   (total 29.9 MB)
    u16* qkb  = (u16*)d_out;          // 12,582,912 u16 == d_out bytes; dead before oproj
    u16* obuf = zb;                   // zb dead after qkv_gemm
    float* out = (float*)d_out;

    convert_all<<<4224, 256, 0, stream>>>(z, wq, wk, wv, wo, zb, wqb, wkb, wvb, wob);
    qkv_gemm<<<1152, 256, 0, stream>>>(zb, wqb, wkb, wvb, qkb, vt);
    attn_kernel<<<dim3(96, 8), 256, 0, stream>>>(qkb, vt, obuf);
    oproj_gemm<<<768, 256, 0, stream>>>(obuf, wob, bo, out);
}